// Round 5
// baseline (2630.914 us; speedup 1.0000x reference)
//
#include <hip/hip_runtime.h>
#include <hip/hip_fp16.h>
#include <math.h>

typedef unsigned short u16;
typedef unsigned int   u32;

// ---------------- dtype adaptivity (validated: inputs are f32/i32; keep as safety) ----
__device__ __forceinline__ bool is_f64(const void* amp){
  u32 u = ((const u32*)amp)[1];
  return ((u >> 20) & 0xFFF) >= 0x3FB;
}
__device__ __forceinline__ bool is_i64(const void* spos){
  const u32* p = (const u32*)spos;
  return (p[1] | p[3] | p[5]) == 0;
}
__device__ __forceinline__ float ldf(const void* p, size_t i, bool f64){
  return f64 ? (float)((const double*)p)[i] : ((const float*)p)[i];
}
__device__ __forceinline__ double lds_scalar(const void* p, bool f64){
  return f64 ? ((const double*)p)[0] : (double)((const float*)p)[0];
}
__device__ __forceinline__ int ldi(const void* p, size_t i, bool i64){
  return i64 ? (int)((const long long*)p)[i] : ((const int*)p)[i];
}

// ---------------- bf16 pack ----------------
__device__ __forceinline__ u16 f2bf(float f){
  u32 u = __float_as_uint(f);
  u32 r = 0x7fffu + ((u >> 16) & 1u);     // RNE
  return (u16)((u + r) >> 16);
}
// FINAL output store: pair order (im, re)
__device__ __forceinline__ void stout(void* p, size_t i, float2 v){
  ((u32*)p)[i] = (u32)f2bf(v.y) | ((u32)f2bf(v.x) << 16);
}

// ---------------- state accessors: H=1 -> fp16 (half2 per complex), H=0 -> fp32 ----
template<int H>
__device__ __forceinline__ float2 ld_state(const void* p, size_t i){
  if (H){
    __half2 h = ((const __half2*)p)[i];
    return __half22float2(h);
  }
  return ((const float2*)p)[i];
}
template<int H>
__device__ __forceinline__ void st_state(void* p, size_t i, float2 v){
  if (H) ((__half2*)p)[i] = __floats2half2_rn(v.x, v.y);
  else   ((float2*)p)[i] = v;
}

// ---------------- complex helpers ----------------
__device__ __forceinline__ float2 cadd(float2 a, float2 b){ return make_float2(a.x+b.x, a.y+b.y); }
__device__ __forceinline__ float2 csub(float2 a, float2 b){ return make_float2(a.x-b.x, a.y-b.y); }
__device__ __forceinline__ float2 cmul(float2 a, float2 b){ return make_float2(a.x*b.x - a.y*b.y, a.x*b.y + a.y*b.x); }
__device__ __forceinline__ float2 cscale(float2 a, float s){ return make_float2(a.x*s, a.y*s); }

template<int SGN>
__device__ __forceinline__ void fft4(float2& a, float2& b, float2& c, float2& d){
  float2 apc = cadd(a,c), amc = csub(a,c);
  float2 bpd = cadd(b,d), bmd = csub(b,d);
  float2 jb = (SGN < 0) ? make_float2(bmd.y, -bmd.x) : make_float2(-bmd.y, bmd.x);
  a = cadd(apc, bpd);
  b = cadd(amc, jb);
  c = csub(apc, bpd);
  d = csub(amc, jb);
}
template<int SGN>
__device__ __forceinline__ float2 twc(float2 z, float re, float im){
  float i2 = (SGN < 0) ? im : -im;
  return make_float2(z.x*re - z.y*i2, z.x*i2 + z.y*re);
}
template<int SGN>
__device__ __forceinline__ void fft16(float2 v[16]){
  float2 h[16];
#pragma unroll
  for (int n1=0;n1<4;n1++){
    float2 a=v[n1], b=v[n1+4], c=v[n1+8], d=v[n1+12];
    fft4<SGN>(a,b,c,d);
    h[n1*4+0]=a; h[n1*4+1]=b; h[n1*4+2]=c; h[n1*4+3]=d;
  }
  const float C1=0.92387953251f, S1=0.38268343236f, C2=0.70710678119f;
  h[5]  = twc<SGN>(h[5],  C1,-S1);
  h[6]  = twc<SGN>(h[6],  C2,-C2);
  h[7]  = twc<SGN>(h[7],  S1,-C1);
  h[9]  = twc<SGN>(h[9],  C2,-C2);
  h[10] = twc<SGN>(h[10], 0.f,-1.f);
  h[11] = twc<SGN>(h[11],-C2,-C2);
  h[13] = twc<SGN>(h[13], S1,-C1);
  h[14] = twc<SGN>(h[14],-C2,-C2);
  h[15] = twc<SGN>(h[15],-C1, S1);
#pragma unroll
  for (int q=0;q<4;q++){
    float2 a=h[q], b=h[4+q], c=h[8+q], d=h[12+q];
    fft4<SGN>(a,b,c,d);
    v[q]=a; v[q+4]=b; v[q+8]=c; v[q+12]=d;
  }
}

// ---------------- fft256 via LDS transpose, half2-packed ----------------
// LDS buffer is half2 (re,im packed in 4B): halves LDS footprint (33->16.5KB,
// occupancy cap 4->6 blocks/CU) and halves the LDS op count (32->16 per fft256).
// Precision: one extra fp16 RNE rounding per fft256 at the same relative scale
// as the fp16 state storage, which measured absmax-neutral in round 4.
// Twiddle: w^q = w1^(q&3) * w4^(q>>2) -- dependency depth ~4 instead of the
// 15-deep serial cmul chain (latency-bound kernel, chain sat before the barrier).
template<int SGN>
__device__ __forceinline__ void fft256(float2 v[16], __half2* T, int g, int t){
  fft16<SGN>(v);
  float s1, c1, s4, c4;
  sincosf(0.0245436926f * (float)t, &s1, &c1);        // 2*pi/256 * t
  sincosf(0.0981747704f * (float)t, &s4, &c4);        // 4 * 2*pi/256 * t
  float2 w1 = make_float2(c1, (SGN < 0) ? -s1 : s1);
  float2 w4 = make_float2(c4, (SGN < 0) ? -s4 : s4);
  float2 p1[4], p4[4];
  p1[0] = make_float2(1.f, 0.f); p1[1] = w1; p1[2] = cmul(w1, w1); p1[3] = cmul(p1[2], w1);
  p4[0] = make_float2(1.f, 0.f); p4[1] = w4; p4[2] = cmul(w4, w4); p4[3] = cmul(p4[2], w4);
#pragma unroll
  for (int q=1;q<16;q++){
    // q compile-time in unrolled loop: p4[0]/p1[0] factors fold to identity
    float2 tw = (q < 4) ? p1[q] : ((q & 3) == 0 ? p4[q>>2] : cmul(p1[q&3], p4[q>>2]));
    v[q] = cmul(v[q], tw);
  }
  int base = g*257;
  __syncthreads();
#pragma unroll
  for (int k1=0;k1<16;k1++){
    int o = base + t*16 + (k1^t);
    T[o] = __floats2half2_rn(v[k1].x, v[k1].y);
  }
  __syncthreads();
#pragma unroll
  for (int n1=0;n1<16;n1++){
    int o = base + n1*16 + (t^n1);
    v[n1] = __half22float2(T[o]);
  }
  fft16<SGN>(v);
  if (SGN > 0){
#pragma unroll
    for (int q=0;q<16;q++) v[q] = cscale(v[q], 1.f/256.f);
  }
}

__device__ __forceinline__ float ffreq(int i){ return (float)(i < 128 ? i : i - 256) * 0.0390625f; }

#define LDS_F 4112
#define KMAX  1.26903553299f   // 0.025/0.0197
#define PHCONST 0.123778191f   // pi*lambda*dz = pi*0.0197*2.0

// ================== main path ==================
// d_out scratch layout (overwritten by the final pass, which writes every byte):
//   probe  at d_out + 0        (512 KB, float2[256*256])
//   ptmp   at d_out + 512 KB   (512 KB)
//   htab   at d_out + 1 MB     (512 KB)
// ws layout: state [B,256,256] (half2 if H, float2 else) at 0; ttab (8x1024x1024
// float2, 64 MB) after it if ws fits.

// ---------------- probe rows ----------------
__global__ void __launch_bounds__(256) probe_rowsF(const void* defocus, const void* Cs,
                                                   const void* astig_mag, const void* astig_angle,
                                                   const void* ap_smooth, const void* ampflag,
                                                   float2* tmp){
  __shared__ __half2 T[LDS_F];
  bool f64 = is_f64(ampflag);
  int tid = threadIdx.x, g = tid>>4, t = tid&15;
  int r = blockIdx.x*16 + g;
  double df = lds_scalar(defocus, f64), cs = lds_scalar(Cs, f64);
  double am = lds_scalar(astig_mag, f64), aa = lds_scalar(astig_angle, f64);
  float sm = fabsf((float)lds_scalar(ap_smooth, f64)) + 0.01f;
  const double LAMd = 0.0197;
  float kxv = ffreq(r);
  float2 v[16];
#pragma unroll
  for (int j=0;j<16;j++){
    int c = t + 16*j;
    float kyv = ffreq(c);
    double k2 = (double)kxv*kxv + (double)kyv*kyv;
    float k  = sqrtf((float)k2);
    double ang = atan2((double)kyv, (double)kxv);
    double chi = M_PI*LAMd*df*k2
               + 0.5*M_PI*LAMd*LAMd*LAMd*(cs*1e6)*k2*k2
               + M_PI*LAMd*am*k2*cos(2.0*(ang - aa));
    float ap = 1.f/(1.f + expf(-(KMAX - k)/(KMAX*sm)));
    double sc = sin(chi), cc = cos(chi);
    v[j] = make_float2(ap*(float)cc, ap*(float)sc);
  }
  fft256<1>(v, T, g, t);
#pragma unroll
  for (int j=0;j<16;j++) tmp[(r<<8) + t + 16*j] = v[j];
}

// ---------------- probe cols ----------------
__global__ void __launch_bounds__(256) probe_colsF(const float2* tmp, float2* probe_out,
                                                   const void* ap_smooth, const void* ampflag){
  __shared__ __half2 T[LDS_F];
  __shared__ float Ssum[4];
  bool f64 = is_f64(ampflag);
  int tid = threadIdx.x, xl = tid&15, t = tid>>4;
  int cx = blockIdx.x*16 + xl;
  float sm = fabsf((float)lds_scalar(ap_smooth, f64)) + 0.01f;
  float S = 0.f;
  for (int i = tid; i < 65536; i += 256){
    float kx = ffreq(i>>8), ky = ffreq(i&255);
    float k = sqrtf(kx*kx + ky*ky);
    float ap = 1.f/(1.f + expf(-(KMAX - k)/(KMAX*sm)));
    S += ap*ap;
  }
#pragma unroll
  for (int off=32; off>0; off>>=1) S += __shfl_down(S, off);
  if ((tid&63)==0) Ssum[tid>>6] = S;
  __syncthreads();
  float scale = 256.f * rsqrtf(Ssum[0]+Ssum[1]+Ssum[2]+Ssum[3]);
  float2 v[16];
#pragma unroll
  for (int j=0;j<16;j++) v[j] = tmp[((t+16*j)<<8) + cx];
  fft256<1>(v, T, xl, t);
  int csh = (cx + 128) & 255;
#pragma unroll
  for (int j=0;j<16;j++){
    int y = t + 16*j;
    probe_out[(((y+128)&255)<<8) + csh] = cscale(v[j], scale);
  }
}

// ---------------- propagator table (65536 float2, computed once) ----------------
__global__ void __launch_bounds__(256) build_htabF(float2* htab){
  int tid = threadIdx.x;
#pragma unroll
  for (int k=0;k<4;k++){
    int i = blockIdx.x*1024 + tid + 256*k;
    float ky = ffreq(i>>8), kx = ffreq(i&255);
    float a = PHCONST*(kx*kx + ky*ky);
    float sa, ca; sincosf(a, &sa, &ca);
    htab[i] = make_float2(ca, sa);
  }
}

// ---------------- transmission table (8x1024x1024 float2, computed once) --------
__global__ void __launch_bounds__(256) build_ttabF(const void* amp, const void* phase,
                                                   float2* ttab){
  bool f64 = is_f64(amp);
  int tid = threadIdx.x;
#pragma unroll
  for (int k=0;k<4;k++){
    size_t i = (size_t)blockIdx.x*1024 + tid + 256*k;
    float A = ldf(amp, i, f64);
    float P = ldf(phase, i, f64);
    float sp, cp; sincosf(P, &sp, &cp);
    ttab[i] = make_float2(A*cp, A*sp);
  }
}

// ---------------- row pass: transmission PREFETCHED before FFT#1 ----------------
// Measured (round 3): 93 -> 64 us from prefetch + direct probe read (no bcast).
template<int H>
__global__ void __launch_bounds__(256, 6) row_passT(const void* amp, const void* phase,
                                                 const void* spos, const void* sidx,
                                                 void* state, const float2* probe,
                                                 const float2* ttab, int s, int first,
                                                 int use_tt){
  __shared__ __half2 T[LDS_F];
  bool f64 = is_f64(amp);
  bool i64 = is_i64(spos);
  int tid = threadIdx.x, g = tid>>4, t = tid&15;
  int b = blockIdx.y;
  int y = blockIdx.x*16 + g;
  int n = ldi(sidx, b, i64);
  int py = ldi(spos, 2*(size_t)n, i64), px = ldi(spos, 2*(size_t)n+1, i64);
  size_t rowbase = ((size_t)s<<20) + (size_t)(py+y)*1024 + px;
  float2 tv[16];
  if (use_tt){
#pragma unroll
    for (int j=0;j<16;j++) tv[j] = ttab[rowbase + t + 16*j];
  } else {
#pragma unroll
    for (int j=0;j<16;j++){
      int x = t + 16*j;
      float A = ldf(amp,   rowbase + x, f64);
      float P = ldf(phase, rowbase + x, f64);
      float sp, cp; sincosf(P, &sp, &cp);
      tv[j] = make_float2(A*cp, A*sp);
    }
  }
  size_t ib = (size_t)b << 16;
  float2 v[16];
  if (first){
#pragma unroll
    for (int j=0;j<16;j++) v[j] = probe[(y<<8) + t + 16*j];
  } else {
#pragma unroll
    for (int j=0;j<16;j++) v[j] = ld_state<H>(state, ib + (y<<8) + t + 16*j);
    fft256<1>(v, T, g, t);
  }
#pragma unroll
  for (int j=0;j<16;j++) v[j] = cmul(v[j], tv[j]);
  fft256<-1>(v, T, g, t);
#pragma unroll
  for (int j=0;j<16;j++) st_state<H>(state, ib + (y<<8) + t + 16*j, v[j]);
}

// ---------------- col pass: H table PREFETCHED before FFT#1 ----------------
template<int H>
__global__ void __launch_bounds__(256, 6) col_passT(void* state, const float2* htab,
                                                 void* outp, int last){
  __shared__ __half2 T[LDS_F];
  int tid = threadIdx.x, xl = tid&15, t = tid>>4;
  int b = blockIdx.y;
  int cx = blockIdx.x*16 + xl;
  size_t ib = (size_t)b << 16;
  float2 v[16], hv[16];
#pragma unroll
  for (int j=0;j<16;j++) v[j] = ld_state<H>(state, ib + ((t+16*j)<<8) + cx);
  if (!last){
#pragma unroll
    for (int j=0;j<16;j++) hv[j] = htab[((t+16*j)<<8) + cx];
  }
  fft256<-1>(v, T, xl, t);
  if (!last){
#pragma unroll
    for (int j=0;j<16;j++) v[j] = cmul(v[j], hv[j]);
    fft256<1>(v, T, xl, t);
#pragma unroll
    for (int j=0;j<16;j++) st_state<H>(state, ib + ((t+16*j)<<8) + cx, v[j]);
  } else {
    // final psi -> d_out as bf16 pairs in (im, re) order
#pragma unroll
    for (int j=0;j<16;j++) stout(outp, ib + ((t+16*j)<<8) + cx, v[j]);
  }
}

template<int H>
static void run_new(const void* amp, const void* phase,
                    const void* df, const void* cs, const void* am, const void* aa,
                    const void* sm, const void* spos, const void* sidx, int B,
                    void* state, float2* ttab, int use_tt,
                    void* dout, hipStream_t stream){
  char* dob = (char*)dout;
  float2* probe = (float2*)dob;
  float2* ptmp  = (float2*)(dob + 524288);
  float2* htab  = (float2*)(dob + 1048576);
  probe_rowsF<<<16, 256, 0, stream>>>(df, cs, am, aa, sm, amp, ptmp);
  probe_colsF<<<16, 256, 0, stream>>>(ptmp, probe, sm, amp);
  build_htabF<<<64, 256, 0, stream>>>(htab);
  if (use_tt) build_ttabF<<<8192, 256, 0, stream>>>(amp, phase, ttab);
  dim3 grid(16, B);
  row_passT<H><<<grid, 256, 0, stream>>>(amp, phase, spos, sidx, state, probe, ttab, 0, 1, use_tt);
  col_passT<H><<<grid, 256, 0, stream>>>(state, htab, dout, 0);
  for (int s = 1; s < 8; s++){
    row_passT<H><<<grid, 256, 0, stream>>>(amp, phase, spos, sidx, state, probe, ttab, s, 0, use_tt);
    col_passT<H><<<grid, 256, 0, stream>>>(state, htab, dout, 0);
  }
  col_passT<H><<<grid, 256, 0, stream>>>(state, htab, dout, 1);
}

extern "C" void kernel_launch(void* const* d_in, const int* in_sizes, int n_in,
                              void* d_out, int out_size, void* d_ws, size_t ws_size,
                              hipStream_t stream) {
  const void* amp   = d_in[0];
  const void* phase = d_in[1];
  const void* df    = d_in[2];
  const void* cs    = d_in[3];
  const void* am    = d_in[4];
  const void* aa    = d_in[5];
  const void* sm    = d_in[6];
  const void* spos  = d_in[7];
  const void* sidx  = d_in[8];
  int B = in_sizes[8];
  (void)out_size; (void)n_in;

  size_t stateH = (size_t)B * 65536 * 4;            // fp16 state [B,256,256] c32 (half2)
  size_t stateF = (size_t)B * 65536 * 8;            // fp32 state fallback
  const size_t ttabB = (size_t)8 * 1024 * 1024 * 8; // 64 MB transmission table
  if (ws_size >= stateH + ttabB){
    void*   state = d_ws;
    float2* ttab  = (float2*)((char*)d_ws + stateH);
    run_new<1>(amp, phase, df, cs, am, aa, sm, spos, sidx, B,
               state, ttab, 1, d_out, stream);
  } else if (ws_size >= stateH){
    run_new<1>(amp, phase, df, cs, am, aa, sm, spos, sidx, B,
               d_ws, (float2*)d_ws, 0, d_out, stream);
  } else {
    // no workspace: fp16 state lives in d_out itself (256KB/slot), tables inline
    run_new<1>(amp, phase, df, cs, am, aa, sm, spos, sidx, B,
               d_out, (float2*)d_out, 0, d_out, stream);
  }
}

// Round 6
// 1011.013 us; speedup vs baseline: 2.6023x; 2.6023x over previous
//
#include <hip/hip_runtime.h>
#include <hip/hip_fp16.h>
#include <math.h>

typedef unsigned short u16;
typedef unsigned int   u32;

// ---------------- dtype adaptivity (validated: inputs are f32/i32; keep as safety) ----
__device__ __forceinline__ bool is_f64(const void* amp){
  u32 u = ((const u32*)amp)[1];
  return ((u >> 20) & 0xFFF) >= 0x3FB;
}
__device__ __forceinline__ bool is_i64(const void* spos){
  const u32* p = (const u32*)spos;
  return (p[1] | p[3] | p[5]) == 0;
}
__device__ __forceinline__ float ldf(const void* p, size_t i, bool f64){
  return f64 ? (float)((const double*)p)[i] : ((const float*)p)[i];
}
__device__ __forceinline__ double lds_scalar(const void* p, bool f64){
  return f64 ? ((const double*)p)[0] : (double)((const float*)p)[0];
}
__device__ __forceinline__ int ldi(const void* p, size_t i, bool i64){
  return i64 ? (int)((const long long*)p)[i] : ((const int*)p)[i];
}

// ---------------- bf16 pack ----------------
__device__ __forceinline__ u16 f2bf(float f){
  u32 u = __float_as_uint(f);
  u32 r = 0x7fffu + ((u >> 16) & 1u);     // RNE
  return (u16)((u + r) >> 16);
}
// FINAL output store: pair order (im, re)
__device__ __forceinline__ void stout(void* p, size_t i, float2 v){
  ((u32*)p)[i] = (u32)f2bf(v.y) | ((u32)f2bf(v.x) << 16);
}

// ---------------- state accessors: H=1 -> fp16 (half2 per complex), H=0 -> fp32 ----
template<int H>
__device__ __forceinline__ float2 ld_state(const void* p, size_t i){
  if (H){
    __half2 h = ((const __half2*)p)[i];
    return __half22float2(h);
  }
  return ((const float2*)p)[i];
}
template<int H>
__device__ __forceinline__ void st_state(void* p, size_t i, float2 v){
  if (H) ((__half2*)p)[i] = __floats2half2_rn(v.x, v.y);
  else   ((float2*)p)[i] = v;
}

// ---------------- complex helpers ----------------
__device__ __forceinline__ float2 cadd(float2 a, float2 b){ return make_float2(a.x+b.x, a.y+b.y); }
__device__ __forceinline__ float2 csub(float2 a, float2 b){ return make_float2(a.x-b.x, a.y-b.y); }
__device__ __forceinline__ float2 cmul(float2 a, float2 b){ return make_float2(a.x*b.x - a.y*b.y, a.x*b.y + a.y*b.x); }
__device__ __forceinline__ float2 cscale(float2 a, float s){ return make_float2(a.x*s, a.y*s); }

template<int SGN>
__device__ __forceinline__ void fft4(float2& a, float2& b, float2& c, float2& d){
  float2 apc = cadd(a,c), amc = csub(a,c);
  float2 bpd = cadd(b,d), bmd = csub(b,d);
  float2 jb = (SGN < 0) ? make_float2(bmd.y, -bmd.x) : make_float2(-bmd.y, bmd.x);
  a = cadd(apc, bpd);
  b = cadd(amc, jb);
  c = csub(apc, bpd);
  d = csub(amc, jb);
}
template<int SGN>
__device__ __forceinline__ float2 twc(float2 z, float re, float im){
  float i2 = (SGN < 0) ? im : -im;
  return make_float2(z.x*re - z.y*i2, z.x*i2 + z.y*re);
}
template<int SGN>
__device__ __forceinline__ void fft16(float2 v[16]){
  float2 h[16];
#pragma unroll
  for (int n1=0;n1<4;n1++){
    float2 a=v[n1], b=v[n1+4], c=v[n1+8], d=v[n1+12];
    fft4<SGN>(a,b,c,d);
    h[n1*4+0]=a; h[n1*4+1]=b; h[n1*4+2]=c; h[n1*4+3]=d;
  }
  const float C1=0.92387953251f, S1=0.38268343236f, C2=0.70710678119f;
  h[5]  = twc<SGN>(h[5],  C1,-S1);
  h[6]  = twc<SGN>(h[6],  C2,-C2);
  h[7]  = twc<SGN>(h[7],  S1,-C1);
  h[9]  = twc<SGN>(h[9],  C2,-C2);
  h[10] = twc<SGN>(h[10], 0.f,-1.f);
  h[11] = twc<SGN>(h[11],-C2,-C2);
  h[13] = twc<SGN>(h[13], S1,-C1);
  h[14] = twc<SGN>(h[14],-C2,-C2);
  h[15] = twc<SGN>(h[15],-C1, S1);
#pragma unroll
  for (int q=0;q<4;q++){
    float2 a=h[q], b=h[4+q], c=h[8+q], d=h[12+q];
    fft4<SGN>(a,b,c,d);
    v[q]=a; v[q+4]=b; v[q+8]=c; v[q+12]=d;
  }
}

// ---------------- fft256 via LDS transpose, half2-packed ----------------
// LDS buffer is half2 (re,im packed in 4B): halves LDS footprint (33->16.5KB,
// occupancy cap 4->9 blocks/CU) and halves the LDS op count (32->16 per fft256).
// Measured round 5: LDS_Block_Size 33280->16896, bank conflicts 4.19M->2.10M. OK.
// Twiddle: w^q = w1^(q&3) * w4^(q>>2) -- dependency depth ~4 instead of 15.
// NOTE: do NOT add a min-waves arg to __launch_bounds__ here. (256,6) forced the
// allocator to VGPR=40 -> v[16] spilled to scratch -> WRITE_SIZE 65MB->725MB,
// 5x slowdown (round-5 counters). Natural allocation gives ~84 VGPR, 6 waves/SIMD.
template<int SGN>
__device__ __forceinline__ void fft256(float2 v[16], __half2* T, int g, int t){
  fft16<SGN>(v);
  float s1, c1, s4, c4;
  sincosf(0.0245436926f * (float)t, &s1, &c1);        // 2*pi/256 * t
  sincosf(0.0981747704f * (float)t, &s4, &c4);        // 4 * 2*pi/256 * t
  float2 w1 = make_float2(c1, (SGN < 0) ? -s1 : s1);
  float2 w4 = make_float2(c4, (SGN < 0) ? -s4 : s4);
  float2 p1[4], p4[4];
  p1[0] = make_float2(1.f, 0.f); p1[1] = w1; p1[2] = cmul(w1, w1); p1[3] = cmul(p1[2], w1);
  p4[0] = make_float2(1.f, 0.f); p4[1] = w4; p4[2] = cmul(w4, w4); p4[3] = cmul(p4[2], w4);
#pragma unroll
  for (int q=1;q<16;q++){
    // q compile-time in unrolled loop: p4[0]/p1[0] factors fold to identity
    float2 tw = (q < 4) ? p1[q] : ((q & 3) == 0 ? p4[q>>2] : cmul(p1[q&3], p4[q>>2]));
    v[q] = cmul(v[q], tw);
  }
  int base = g*257;
  __syncthreads();
#pragma unroll
  for (int k1=0;k1<16;k1++){
    int o = base + t*16 + (k1^t);
    T[o] = __floats2half2_rn(v[k1].x, v[k1].y);
  }
  __syncthreads();
#pragma unroll
  for (int n1=0;n1<16;n1++){
    int o = base + n1*16 + (t^n1);
    v[n1] = __half22float2(T[o]);
  }
  fft16<SGN>(v);
  if (SGN > 0){
#pragma unroll
    for (int q=0;q<16;q++) v[q] = cscale(v[q], 1.f/256.f);
  }
}

__device__ __forceinline__ float ffreq(int i){ return (float)(i < 128 ? i : i - 256) * 0.0390625f; }

#define LDS_F 4112
#define KMAX  1.26903553299f   // 0.025/0.0197
#define PHCONST 0.123778191f   // pi*lambda*dz = pi*0.0197*2.0

// ================== main path ==================
// d_out scratch layout (overwritten by the final pass, which writes every byte):
//   probe  at d_out + 0        (512 KB, float2[256*256])
//   ptmp   at d_out + 512 KB   (512 KB)
//   htab   at d_out + 1 MB     (512 KB)
// ws layout: state [B,256,256] half2 at 0; ttab (8x1024x1024 float2, 64 MB) after.

// ---------------- probe rows ----------------
__global__ void __launch_bounds__(256) probe_rowsF(const void* defocus, const void* Cs,
                                                   const void* astig_mag, const void* astig_angle,
                                                   const void* ap_smooth, const void* ampflag,
                                                   float2* tmp){
  __shared__ __half2 T[LDS_F];
  bool f64 = is_f64(ampflag);
  int tid = threadIdx.x, g = tid>>4, t = tid&15;
  int r = blockIdx.x*16 + g;
  double df = lds_scalar(defocus, f64), cs = lds_scalar(Cs, f64);
  double am = lds_scalar(astig_mag, f64), aa = lds_scalar(astig_angle, f64);
  float sm = fabsf((float)lds_scalar(ap_smooth, f64)) + 0.01f;
  const double LAMd = 0.0197;
  float kxv = ffreq(r);
  float2 v[16];
#pragma unroll
  for (int j=0;j<16;j++){
    int c = t + 16*j;
    float kyv = ffreq(c);
    double k2 = (double)kxv*kxv + (double)kyv*kyv;
    float k  = sqrtf((float)k2);
    double ang = atan2((double)kyv, (double)kxv);
    double chi = M_PI*LAMd*df*k2
               + 0.5*M_PI*LAMd*LAMd*LAMd*(cs*1e6)*k2*k2
               + M_PI*LAMd*am*k2*cos(2.0*(ang - aa));
    float ap = 1.f/(1.f + expf(-(KMAX - k)/(KMAX*sm)));
    double sc = sin(chi), cc = cos(chi);
    v[j] = make_float2(ap*(float)cc, ap*(float)sc);
  }
  fft256<1>(v, T, g, t);
#pragma unroll
  for (int j=0;j<16;j++) tmp[(r<<8) + t + 16*j] = v[j];
}

// ---------------- probe cols ----------------
__global__ void __launch_bounds__(256) probe_colsF(const float2* tmp, float2* probe_out,
                                                   const void* ap_smooth, const void* ampflag){
  __shared__ __half2 T[LDS_F];
  __shared__ float Ssum[4];
  bool f64 = is_f64(ampflag);
  int tid = threadIdx.x, xl = tid&15, t = tid>>4;
  int cx = blockIdx.x*16 + xl;
  float sm = fabsf((float)lds_scalar(ap_smooth, f64)) + 0.01f;
  float S = 0.f;
  for (int i = tid; i < 65536; i += 256){
    float kx = ffreq(i>>8), ky = ffreq(i&255);
    float k = sqrtf(kx*kx + ky*ky);
    float ap = 1.f/(1.f + expf(-(KMAX - k)/(KMAX*sm)));
    S += ap*ap;
  }
#pragma unroll
  for (int off=32; off>0; off>>=1) S += __shfl_down(S, off);
  if ((tid&63)==0) Ssum[tid>>6] = S;
  __syncthreads();
  float scale = 256.f * rsqrtf(Ssum[0]+Ssum[1]+Ssum[2]+Ssum[3]);
  float2 v[16];
#pragma unroll
  for (int j=0;j<16;j++) v[j] = tmp[((t+16*j)<<8) + cx];
  fft256<1>(v, T, xl, t);
  int csh = (cx + 128) & 255;
#pragma unroll
  for (int j=0;j<16;j++){
    int y = t + 16*j;
    probe_out[(((y+128)&255)<<8) + csh] = cscale(v[j], scale);
  }
}

// ---------------- propagator table (65536 float2, computed once) ----------------
__global__ void __launch_bounds__(256) build_htabF(float2* htab){
  int tid = threadIdx.x;
#pragma unroll
  for (int k=0;k<4;k++){
    int i = blockIdx.x*1024 + tid + 256*k;
    float ky = ffreq(i>>8), kx = ffreq(i&255);
    float a = PHCONST*(kx*kx + ky*ky);
    float sa, ca; sincosf(a, &sa, &ca);
    htab[i] = make_float2(ca, sa);
  }
}

// ---------------- transmission table (8x1024x1024 float2, computed once) --------
__global__ void __launch_bounds__(256) build_ttabF(const void* amp, const void* phase,
                                                   float2* ttab){
  bool f64 = is_f64(amp);
  int tid = threadIdx.x;
#pragma unroll
  for (int k=0;k<4;k++){
    size_t i = (size_t)blockIdx.x*1024 + tid + 256*k;
    float A = ldf(amp, i, f64);
    float P = ldf(phase, i, f64);
    float sp, cp; sincosf(P, &sp, &cp);
    ttab[i] = make_float2(A*cp, A*sp);
  }
}

// ---------------- row pass: transmission PREFETCHED before FFT#1 ----------------
// Measured (round 3): 93 -> 64 us from prefetch + direct probe read (no bcast).
template<int H>
__global__ void __launch_bounds__(256) row_passT(const void* amp, const void* phase,
                                                 const void* spos, const void* sidx,
                                                 void* state, const float2* probe,
                                                 const float2* ttab, int s, int first,
                                                 int use_tt){
  __shared__ __half2 T[LDS_F];
  bool f64 = is_f64(amp);
  bool i64 = is_i64(spos);
  int tid = threadIdx.x, g = tid>>4, t = tid&15;
  int b = blockIdx.y;
  int y = blockIdx.x*16 + g;
  int n = ldi(sidx, b, i64);
  int py = ldi(spos, 2*(size_t)n, i64), px = ldi(spos, 2*(size_t)n+1, i64);
  size_t rowbase = ((size_t)s<<20) + (size_t)(py+y)*1024 + px;
  float2 tv[16];
  if (use_tt){
#pragma unroll
    for (int j=0;j<16;j++) tv[j] = ttab[rowbase + t + 16*j];
  } else {
#pragma unroll
    for (int j=0;j<16;j++){
      int x = t + 16*j;
      float A = ldf(amp,   rowbase + x, f64);
      float P = ldf(phase, rowbase + x, f64);
      float sp, cp; sincosf(P, &sp, &cp);
      tv[j] = make_float2(A*cp, A*sp);
    }
  }
  size_t ib = (size_t)b << 16;
  float2 v[16];
  if (first){
#pragma unroll
    for (int j=0;j<16;j++) v[j] = probe[(y<<8) + t + 16*j];
  } else {
#pragma unroll
    for (int j=0;j<16;j++) v[j] = ld_state<H>(state, ib + (y<<8) + t + 16*j);
    fft256<1>(v, T, g, t);
  }
#pragma unroll
  for (int j=0;j<16;j++) v[j] = cmul(v[j], tv[j]);
  fft256<-1>(v, T, g, t);
#pragma unroll
  for (int j=0;j<16;j++) st_state<H>(state, ib + (y<<8) + t + 16*j, v[j]);
}

// ---------------- col pass: H table PREFETCHED before FFT#1 ----------------
template<int H>
__global__ void __launch_bounds__(256) col_passT(void* state, const float2* htab,
                                                 void* outp, int last){
  __shared__ __half2 T[LDS_F];
  int tid = threadIdx.x, xl = tid&15, t = tid>>4;
  int b = blockIdx.y;
  int cx = blockIdx.x*16 + xl;
  size_t ib = (size_t)b << 16;
  float2 v[16], hv[16];
#pragma unroll
  for (int j=0;j<16;j++) v[j] = ld_state<H>(state, ib + ((t+16*j)<<8) + cx);
  if (!last){
#pragma unroll
    for (int j=0;j<16;j++) hv[j] = htab[((t+16*j)<<8) + cx];
  }
  fft256<-1>(v, T, xl, t);
  if (!last){
#pragma unroll
    for (int j=0;j<16;j++) v[j] = cmul(v[j], hv[j]);
    fft256<1>(v, T, xl, t);
#pragma unroll
    for (int j=0;j<16;j++) st_state<H>(state, ib + ((t+16*j)<<8) + cx, v[j]);
  } else {
    // final psi -> d_out as bf16 pairs in (im, re) order
#pragma unroll
    for (int j=0;j<16;j++) stout(outp, ib + ((t+16*j)<<8) + cx, v[j]);
  }
}

template<int H>
static void run_new(const void* amp, const void* phase,
                    const void* df, const void* cs, const void* am, const void* aa,
                    const void* sm, const void* spos, const void* sidx, int B,
                    void* state, float2* ttab, int use_tt,
                    void* dout, hipStream_t stream){
  char* dob = (char*)dout;
  float2* probe = (float2*)dob;
  float2* ptmp  = (float2*)(dob + 524288);
  float2* htab  = (float2*)(dob + 1048576);
  probe_rowsF<<<16, 256, 0, stream>>>(df, cs, am, aa, sm, amp, ptmp);
  probe_colsF<<<16, 256, 0, stream>>>(ptmp, probe, sm, amp);
  build_htabF<<<64, 256, 0, stream>>>(htab);
  if (use_tt) build_ttabF<<<8192, 256, 0, stream>>>(amp, phase, ttab);
  dim3 grid(16, B);
  row_passT<H><<<grid, 256, 0, stream>>>(amp, phase, spos, sidx, state, probe, ttab, 0, 1, use_tt);
  col_passT<H><<<grid, 256, 0, stream>>>(state, htab, dout, 0);
  for (int s = 1; s < 8; s++){
    row_passT<H><<<grid, 256, 0, stream>>>(amp, phase, spos, sidx, state, probe, ttab, s, 0, use_tt);
    col_passT<H><<<grid, 256, 0, stream>>>(state, htab, dout, 0);
  }
  col_passT<H><<<grid, 256, 0, stream>>>(state, htab, dout, 1);
}

extern "C" void kernel_launch(void* const* d_in, const int* in_sizes, int n_in,
                              void* d_out, int out_size, void* d_ws, size_t ws_size,
                              hipStream_t stream) {
  const void* amp   = d_in[0];
  const void* phase = d_in[1];
  const void* df    = d_in[2];
  const void* cs    = d_in[3];
  const void* am    = d_in[4];
  const void* aa    = d_in[5];
  const void* sm    = d_in[6];
  const void* spos  = d_in[7];
  const void* sidx  = d_in[8];
  int B = in_sizes[8];
  (void)out_size; (void)n_in;

  size_t stateH = (size_t)B * 65536 * 4;            // fp16 state [B,256,256] c32 (half2)
  const size_t ttabB = (size_t)8 * 1024 * 1024 * 8; // 64 MB transmission table
  if (ws_size >= stateH + ttabB){
    void*   state = d_ws;
    float2* ttab  = (float2*)((char*)d_ws + stateH);
    run_new<1>(amp, phase, df, cs, am, aa, sm, spos, sidx, B,
               state, ttab, 1, d_out, stream);
  } else if (ws_size >= stateH){
    run_new<1>(amp, phase, df, cs, am, aa, sm, spos, sidx, B,
               d_ws, (float2*)d_ws, 0, d_out, stream);
  } else {
    // no workspace: fp16 state lives in d_out itself (256KB/slot), tables inline
    run_new<1>(amp, phase, df, cs, am, aa, sm, spos, sidx, B,
               d_out, (float2*)d_out, 0, d_out, stream);
  }
}

// Round 7
// 904.729 us; speedup vs baseline: 2.9080x; 1.1175x over previous
//
#include <hip/hip_runtime.h>
#include <hip/hip_fp16.h>
#include <math.h>

typedef unsigned short u16;
typedef unsigned int   u32;

// ---------------- dtype adaptivity (validated: inputs are f32/i32; keep as safety) ----
__device__ __forceinline__ bool is_f64(const void* amp){
  u32 u = ((const u32*)amp)[1];
  return ((u >> 20) & 0xFFF) >= 0x3FB;
}
__device__ __forceinline__ bool is_i64(const void* spos){
  const u32* p = (const u32*)spos;
  return (p[1] | p[3] | p[5]) == 0;
}
__device__ __forceinline__ float ldf(const void* p, size_t i, bool f64){
  return f64 ? (float)((const double*)p)[i] : ((const float*)p)[i];
}
__device__ __forceinline__ double lds_scalar(const void* p, bool f64){
  return f64 ? ((const double*)p)[0] : (double)((const float*)p)[0];
}
__device__ __forceinline__ int ldi(const void* p, size_t i, bool i64){
  return i64 ? (int)((const long long*)p)[i] : ((const int*)p)[i];
}

// ---------------- bf16 pack ----------------
__device__ __forceinline__ u16 f2bf(float f){
  u32 u = __float_as_uint(f);
  u32 r = 0x7fffu + ((u >> 16) & 1u);     // RNE
  return (u16)((u + r) >> 16);
}
// FINAL output store: pair order (im, re)
__device__ __forceinline__ void stout(void* p, size_t i, float2 v){
  ((u32*)p)[i] = (u32)f2bf(v.y) | ((u32)f2bf(v.x) << 16);
}

// ---------------- state accessors: H=1 -> fp16 (half2 per complex), H=0 -> fp32 ----
template<int H>
__device__ __forceinline__ float2 ld_state(const void* p, size_t i){
  if (H){
    __half2 h = ((const __half2*)p)[i];
    return __half22float2(h);
  }
  return ((const float2*)p)[i];
}
template<int H>
__device__ __forceinline__ void st_state(void* p, size_t i, float2 v){
  if (H) ((__half2*)p)[i] = __floats2half2_rn(v.x, v.y);
  else   ((float2*)p)[i] = v;
}

// ---------------- complex helpers ----------------
__device__ __forceinline__ float2 cadd(float2 a, float2 b){ return make_float2(a.x+b.x, a.y+b.y); }
__device__ __forceinline__ float2 csub(float2 a, float2 b){ return make_float2(a.x-b.x, a.y-b.y); }
__device__ __forceinline__ float2 cmul(float2 a, float2 b){ return make_float2(a.x*b.x - a.y*b.y, a.x*b.y + a.y*b.x); }
__device__ __forceinline__ float2 cscale(float2 a, float s){ return make_float2(a.x*s, a.y*s); }

template<int SGN>
__device__ __forceinline__ void fft4(float2& a, float2& b, float2& c, float2& d){
  float2 apc = cadd(a,c), amc = csub(a,c);
  float2 bpd = cadd(b,d), bmd = csub(b,d);
  float2 jb = (SGN < 0) ? make_float2(bmd.y, -bmd.x) : make_float2(-bmd.y, bmd.x);
  a = cadd(apc, bpd);
  b = cadd(amc, jb);
  c = csub(apc, bpd);
  d = csub(amc, jb);
}
template<int SGN>
__device__ __forceinline__ float2 twc(float2 z, float re, float im){
  float i2 = (SGN < 0) ? im : -im;
  return make_float2(z.x*re - z.y*i2, z.x*i2 + z.y*re);
}
template<int SGN>
__device__ __forceinline__ void fft16(float2 v[16]){
  float2 h[16];
#pragma unroll
  for (int n1=0;n1<4;n1++){
    float2 a=v[n1], b=v[n1+4], c=v[n1+8], d=v[n1+12];
    fft4<SGN>(a,b,c,d);
    h[n1*4+0]=a; h[n1*4+1]=b; h[n1*4+2]=c; h[n1*4+3]=d;
  }
  const float C1=0.92387953251f, S1=0.38268343236f, C2=0.70710678119f;
  h[5]  = twc<SGN>(h[5],  C1,-S1);
  h[6]  = twc<SGN>(h[6],  C2,-C2);
  h[7]  = twc<SGN>(h[7],  S1,-C1);
  h[9]  = twc<SGN>(h[9],  C2,-C2);
  h[10] = twc<SGN>(h[10], 0.f,-1.f);
  h[11] = twc<SGN>(h[11],-C2,-C2);
  h[13] = twc<SGN>(h[13], S1,-C1);
  h[14] = twc<SGN>(h[14],-C2,-C2);
  h[15] = twc<SGN>(h[15],-C1, S1);
#pragma unroll
  for (int q=0;q<4;q++){
    float2 a=h[q], b=h[4+q], c=h[8+q], d=h[12+q];
    fft4<SGN>(a,b,c,d);
    v[q]=a; v[q+4]=b; v[q+8]=c; v[q+12]=d;
  }
}

// ---------------- fft256 via LDS transpose, fp32 buffers ----------------
// ROUND-6 LESSON: half2-packed LDS was a net loss (-11%): LDS capacity was NOT
// the binding resource (VGPR=88 keeps 4 waves/SIMD regardless), and the 96
// pack/unpack cvts per pass taxed an already VALU-heavy kernel. fp32 LDS +
// serial twiddle chain (round-4 form, 905us) is the measured best. BARRIER=0
// variant for kernels whose 16-thread FFT groups are wave-private (row family):
// group g = tid>>4 spans lanes [16g,16g+16) of ONE wave, LDS region g*257 is
// group-private -> no cross-wave sharing -> ds_write->ds_read ordering within
// the single wave's instruction stream is enforced by compiler lgkmcnt waits;
// __syncthreads only coupled 4 independent waves. col family (groups span all
// 4 waves: tid = xl, 16+xl, ...) keeps BARRIER=1.
template<int SGN, int BARRIER>
__device__ __forceinline__ void fft256(float2 v[16], float* Tr, float* Ti, int g, int t){
  fft16<SGN>(v);
  float s0, c0;
  sincosf(0.0245436926f * (float)t, &s0, &c0);   // 2*pi/256 * t
  float2 w1 = make_float2(c0, (SGN < 0) ? -s0 : s0);
  float2 cw = w1;
#pragma unroll
  for (int q=1;q<16;q++){
    v[q] = cmul(v[q], cw);
    if (q < 15) cw = cmul(cw, w1);
  }
  int base = g*257;
  if (BARRIER) __syncthreads();
#pragma unroll
  for (int k1=0;k1<16;k1++){
    int o = base + t*16 + (k1^t);
    Tr[o] = v[k1].x; Ti[o] = v[k1].y;
  }
  if (BARRIER) __syncthreads();
#pragma unroll
  for (int n1=0;n1<16;n1++){
    int o = base + n1*16 + (t^n1);
    v[n1] = make_float2(Tr[o], Ti[o]);
  }
  fft16<SGN>(v);
  if (SGN > 0){
#pragma unroll
    for (int q=0;q<16;q++) v[q] = cscale(v[q], 1.f/256.f);
  }
}

__device__ __forceinline__ float ffreq(int i){ return (float)(i < 128 ? i : i - 256) * 0.0390625f; }

#define LDS_F 4112
#define KMAX  1.26903553299f   // 0.025/0.0197
#define PHCONST 0.123778191f   // pi*lambda*dz = pi*0.0197*2.0

// ================== main path ==================
// d_out scratch layout (overwritten by the final pass, which writes every byte):
//   probe  at d_out + 0        (512 KB, float2[256*256])
//   ptmp   at d_out + 512 KB   (512 KB)
//   htab   at d_out + 1 MB     (512 KB)
// ws layout: state [B,256,256] half2 at 0; ttab (8x1024x1024 float2, 64 MB) after.

// ---------------- probe rows (wave-private FFT groups: no barriers) ----------------
__global__ void __launch_bounds__(256) probe_rowsF(const void* defocus, const void* Cs,
                                                   const void* astig_mag, const void* astig_angle,
                                                   const void* ap_smooth, const void* ampflag,
                                                   float2* tmp){
  __shared__ float Tr[LDS_F], Ti[LDS_F];
  bool f64 = is_f64(ampflag);
  int tid = threadIdx.x, g = tid>>4, t = tid&15;
  int r = blockIdx.x*16 + g;
  double df = lds_scalar(defocus, f64), cs = lds_scalar(Cs, f64);
  double am = lds_scalar(astig_mag, f64), aa = lds_scalar(astig_angle, f64);
  float sm = fabsf((float)lds_scalar(ap_smooth, f64)) + 0.01f;
  const double LAMd = 0.0197;
  float kxv = ffreq(r);
  float2 v[16];
#pragma unroll
  for (int j=0;j<16;j++){
    int c = t + 16*j;
    float kyv = ffreq(c);
    double k2 = (double)kxv*kxv + (double)kyv*kyv;
    float k  = sqrtf((float)k2);
    double ang = atan2((double)kyv, (double)kxv);
    double chi = M_PI*LAMd*df*k2
               + 0.5*M_PI*LAMd*LAMd*LAMd*(cs*1e6)*k2*k2
               + M_PI*LAMd*am*k2*cos(2.0*(ang - aa));
    float ap = 1.f/(1.f + expf(-(KMAX - k)/(KMAX*sm)));
    double sc = sin(chi), cc = cos(chi);
    v[j] = make_float2(ap*(float)cc, ap*(float)sc);
  }
  fft256<1,0>(v, Tr, Ti, g, t);
#pragma unroll
  for (int j=0;j<16;j++) tmp[(r<<8) + t + 16*j] = v[j];
}

// ---------------- probe cols (groups span waves: barriers required) -------------
__global__ void __launch_bounds__(256) probe_colsF(const float2* tmp, float2* probe_out,
                                                   const void* ap_smooth, const void* ampflag){
  __shared__ float Tr[LDS_F], Ti[LDS_F];
  bool f64 = is_f64(ampflag);
  int tid = threadIdx.x, xl = tid&15, t = tid>>4;
  int cx = blockIdx.x*16 + xl;
  float sm = fabsf((float)lds_scalar(ap_smooth, f64)) + 0.01f;
  float S = 0.f;
  for (int i = tid; i < 65536; i += 256){
    float kx = ffreq(i>>8), ky = ffreq(i&255);
    float k = sqrtf(kx*kx + ky*ky);
    float ap = 1.f/(1.f + expf(-(KMAX - k)/(KMAX*sm)));
    S += ap*ap;
  }
#pragma unroll
  for (int off=32; off>0; off>>=1) S += __shfl_down(S, off);
  if ((tid&63)==0) Tr[tid>>6] = S;
  __syncthreads();
  float scale = 256.f * rsqrtf(Tr[0]+Tr[1]+Tr[2]+Tr[3]);
  float2 v[16];
#pragma unroll
  for (int j=0;j<16;j++) v[j] = tmp[((t+16*j)<<8) + cx];
  fft256<1,1>(v, Tr, Ti, xl, t);
  int csh = (cx + 128) & 255;
#pragma unroll
  for (int j=0;j<16;j++){
    int y = t + 16*j;
    probe_out[(((y+128)&255)<<8) + csh] = cscale(v[j], scale);
  }
}

// ---------------- propagator table (65536 float2, computed once) ----------------
__global__ void __launch_bounds__(256) build_htabF(float2* htab){
  int tid = threadIdx.x;
#pragma unroll
  for (int k=0;k<4;k++){
    int i = blockIdx.x*1024 + tid + 256*k;
    float ky = ffreq(i>>8), kx = ffreq(i&255);
    float a = PHCONST*(kx*kx + ky*ky);
    float sa, ca; sincosf(a, &sa, &ca);
    htab[i] = make_float2(ca, sa);
  }
}

// ---------------- transmission table (8x1024x1024 float2, computed once) --------
__global__ void __launch_bounds__(256) build_ttabF(const void* amp, const void* phase,
                                                   float2* ttab){
  bool f64 = is_f64(amp);
  int tid = threadIdx.x;
#pragma unroll
  for (int k=0;k<4;k++){
    size_t i = (size_t)blockIdx.x*1024 + tid + 256*k;
    float A = ldf(amp, i, f64);
    float P = ldf(phase, i, f64);
    float sp, cp; sincosf(P, &sp, &cp);
    ttab[i] = make_float2(A*cp, A*sp);
  }
}

// ---------------- row pass: transmission PREFETCHED before FFT#1; NO barriers ----
// Measured (round 3): 93 -> 64 us from prefetch + direct probe read (no bcast).
template<int H>
__global__ void __launch_bounds__(256) row_passT(const void* amp, const void* phase,
                                                 const void* spos, const void* sidx,
                                                 void* state, const float2* probe,
                                                 const float2* ttab, int s, int first,
                                                 int use_tt){
  __shared__ float Tr[LDS_F], Ti[LDS_F];
  bool f64 = is_f64(amp);
  bool i64 = is_i64(spos);
  int tid = threadIdx.x, g = tid>>4, t = tid&15;
  int b = blockIdx.y;
  int y = blockIdx.x*16 + g;
  int n = ldi(sidx, b, i64);
  int py = ldi(spos, 2*(size_t)n, i64), px = ldi(spos, 2*(size_t)n+1, i64);
  size_t rowbase = ((size_t)s<<20) + (size_t)(py+y)*1024 + px;
  float2 tv[16];
  if (use_tt){
#pragma unroll
    for (int j=0;j<16;j++) tv[j] = ttab[rowbase + t + 16*j];
  } else {
#pragma unroll
    for (int j=0;j<16;j++){
      int x = t + 16*j;
      float A = ldf(amp,   rowbase + x, f64);
      float P = ldf(phase, rowbase + x, f64);
      float sp, cp; sincosf(P, &sp, &cp);
      tv[j] = make_float2(A*cp, A*sp);
    }
  }
  size_t ib = (size_t)b << 16;
  float2 v[16];
  if (first){
#pragma unroll
    for (int j=0;j<16;j++) v[j] = probe[(y<<8) + t + 16*j];
  } else {
#pragma unroll
    for (int j=0;j<16;j++) v[j] = ld_state<H>(state, ib + (y<<8) + t + 16*j);
    fft256<1,0>(v, Tr, Ti, g, t);
  }
#pragma unroll
  for (int j=0;j<16;j++) v[j] = cmul(v[j], tv[j]);
  fft256<-1,0>(v, Tr, Ti, g, t);
#pragma unroll
  for (int j=0;j<16;j++) st_state<H>(state, ib + (y<<8) + t + 16*j, v[j]);
}

// ---------------- col pass: H table PREFETCHED before FFT#1; barriers kept ------
template<int H>
__global__ void __launch_bounds__(256) col_passT(void* state, const float2* htab,
                                                 void* outp, int last){
  __shared__ float Tr[LDS_F], Ti[LDS_F];
  int tid = threadIdx.x, xl = tid&15, t = tid>>4;
  int b = blockIdx.y;
  int cx = blockIdx.x*16 + xl;
  size_t ib = (size_t)b << 16;
  float2 v[16], hv[16];
#pragma unroll
  for (int j=0;j<16;j++) v[j] = ld_state<H>(state, ib + ((t+16*j)<<8) + cx);
  if (!last){
#pragma unroll
    for (int j=0;j<16;j++) hv[j] = htab[((t+16*j)<<8) + cx];
  }
  fft256<-1,1>(v, Tr, Ti, xl, t);
  if (!last){
#pragma unroll
    for (int j=0;j<16;j++) v[j] = cmul(v[j], hv[j]);
    fft256<1,1>(v, Tr, Ti, xl, t);
#pragma unroll
    for (int j=0;j<16;j++) st_state<H>(state, ib + ((t+16*j)<<8) + cx, v[j]);
  } else {
    // final psi -> d_out as bf16 pairs in (im, re) order
#pragma unroll
    for (int j=0;j<16;j++) stout(outp, ib + ((t+16*j)<<8) + cx, v[j]);
  }
}

template<int H>
static void run_new(const void* amp, const void* phase,
                    const void* df, const void* cs, const void* am, const void* aa,
                    const void* sm, const void* spos, const void* sidx, int B,
                    void* state, float2* ttab, int use_tt,
                    void* dout, hipStream_t stream){
  char* dob = (char*)dout;
  float2* probe = (float2*)dob;
  float2* ptmp  = (float2*)(dob + 524288);
  float2* htab  = (float2*)(dob + 1048576);
  probe_rowsF<<<16, 256, 0, stream>>>(df, cs, am, aa, sm, amp, ptmp);
  probe_colsF<<<16, 256, 0, stream>>>(ptmp, probe, sm, amp);
  build_htabF<<<64, 256, 0, stream>>>(htab);
  if (use_tt) build_ttabF<<<8192, 256, 0, stream>>>(amp, phase, ttab);
  dim3 grid(16, B);
  row_passT<H><<<grid, 256, 0, stream>>>(amp, phase, spos, sidx, state, probe, ttab, 0, 1, use_tt);
  col_passT<H><<<grid, 256, 0, stream>>>(state, htab, dout, 0);
  for (int s = 1; s < 8; s++){
    row_passT<H><<<grid, 256, 0, stream>>>(amp, phase, spos, sidx, state, probe, ttab, s, 0, use_tt);
    col_passT<H><<<grid, 256, 0, stream>>>(state, htab, dout, 0);
  }
  col_passT<H><<<grid, 256, 0, stream>>>(state, htab, dout, 1);
}

extern "C" void kernel_launch(void* const* d_in, const int* in_sizes, int n_in,
                              void* d_out, int out_size, void* d_ws, size_t ws_size,
                              hipStream_t stream) {
  const void* amp   = d_in[0];
  const void* phase = d_in[1];
  const void* df    = d_in[2];
  const void* cs    = d_in[3];
  const void* am    = d_in[4];
  const void* aa    = d_in[5];
  const void* sm    = d_in[6];
  const void* spos  = d_in[7];
  const void* sidx  = d_in[8];
  int B = in_sizes[8];
  (void)out_size; (void)n_in;

  size_t stateH = (size_t)B * 65536 * 4;            // fp16 state [B,256,256] c32 (half2)
  const size_t ttabB = (size_t)8 * 1024 * 1024 * 8; // 64 MB transmission table
  if (ws_size >= stateH + ttabB){
    void*   state = d_ws;
    float2* ttab  = (float2*)((char*)d_ws + stateH);
    run_new<1>(amp, phase, df, cs, am, aa, sm, spos, sidx, B,
               state, ttab, 1, d_out, stream);
  } else if (ws_size >= stateH){
    run_new<1>(amp, phase, df, cs, am, aa, sm, spos, sidx, B,
               d_ws, (float2*)d_ws, 0, d_out, stream);
  } else {
    // no workspace: fp16 state lives in d_out itself (256KB/slot), tables inline
    run_new<1>(amp, phase, df, cs, am, aa, sm, spos, sidx, B,
               d_out, (float2*)d_out, 0, d_out, stream);
  }
}

// Round 8
// 838.934 us; speedup vs baseline: 3.1360x; 1.0784x over previous
//
#include <hip/hip_runtime.h>
#include <hip/hip_fp16.h>
#include <math.h>

typedef unsigned short u16;
typedef unsigned int   u32;

// ---------------- dtype adaptivity (validated: inputs are f32/i32; keep as safety) ----
__device__ __forceinline__ bool is_f64(const void* amp){
  u32 u = ((const u32*)amp)[1];
  return ((u >> 20) & 0xFFF) >= 0x3FB;
}
__device__ __forceinline__ bool is_i64(const void* spos){
  const u32* p = (const u32*)spos;
  return (p[1] | p[3] | p[5]) == 0;
}
__device__ __forceinline__ float ldf(const void* p, size_t i, bool f64){
  return f64 ? (float)((const double*)p)[i] : ((const float*)p)[i];
}
__device__ __forceinline__ double lds_scalar(const void* p, bool f64){
  return f64 ? ((const double*)p)[0] : (double)((const float*)p)[0];
}
__device__ __forceinline__ int ldi(const void* p, size_t i, bool i64){
  return i64 ? (int)((const long long*)p)[i] : ((const int*)p)[i];
}

// ---------------- bf16 pack ----------------
__device__ __forceinline__ u16 f2bf(float f){
  u32 u = __float_as_uint(f);
  u32 r = 0x7fffu + ((u >> 16) & 1u);     // RNE
  return (u16)((u + r) >> 16);
}
// FINAL output store: pair order (im, re)
__device__ __forceinline__ void stout(void* p, size_t i, float2 v){
  ((u32*)p)[i] = (u32)f2bf(v.y) | ((u32)f2bf(v.x) << 16);
}

// ---------------- state accessors: H=1 -> fp16 (half2 per complex), H=0 -> fp32 ----
template<int H>
__device__ __forceinline__ float2 ld_state(const void* p, size_t i){
  if (H){
    __half2 h = ((const __half2*)p)[i];
    return __half22float2(h);
  }
  return ((const float2*)p)[i];
}
template<int H>
__device__ __forceinline__ void st_state(void* p, size_t i, float2 v){
  if (H) ((__half2*)p)[i] = __floats2half2_rn(v.x, v.y);
  else   ((float2*)p)[i] = v;
}

// ---------------- complex helpers ----------------
__device__ __forceinline__ float2 cadd(float2 a, float2 b){ return make_float2(a.x+b.x, a.y+b.y); }
__device__ __forceinline__ float2 csub(float2 a, float2 b){ return make_float2(a.x-b.x, a.y-b.y); }
__device__ __forceinline__ float2 cmul(float2 a, float2 b){ return make_float2(a.x*b.x - a.y*b.y, a.x*b.y + a.y*b.x); }
// multiply by conjugate of b
__device__ __forceinline__ float2 cmulc(float2 a, float2 b){ return make_float2(a.x*b.x + a.y*b.y, a.y*b.x - a.x*b.y); }
__device__ __forceinline__ float2 cscale(float2 a, float s){ return make_float2(a.x*s, a.y*s); }

template<int SGN>
__device__ __forceinline__ void fft4(float2& a, float2& b, float2& c, float2& d){
  float2 apc = cadd(a,c), amc = csub(a,c);
  float2 bpd = cadd(b,d), bmd = csub(b,d);
  float2 jb = (SGN < 0) ? make_float2(bmd.y, -bmd.x) : make_float2(-bmd.y, bmd.x);
  a = cadd(apc, bpd);
  b = cadd(amc, jb);
  c = csub(apc, bpd);
  d = csub(amc, jb);
}
template<int SGN>
__device__ __forceinline__ float2 twc(float2 z, float re, float im){
  float i2 = (SGN < 0) ? im : -im;
  return make_float2(z.x*re - z.y*i2, z.x*i2 + z.y*re);
}
template<int SGN>
__device__ __forceinline__ void fft16(float2 v[16]){
  float2 h[16];
#pragma unroll
  for (int n1=0;n1<4;n1++){
    float2 a=v[n1], b=v[n1+4], c=v[n1+8], d=v[n1+12];
    fft4<SGN>(a,b,c,d);
    h[n1*4+0]=a; h[n1*4+1]=b; h[n1*4+2]=c; h[n1*4+3]=d;
  }
  const float C1=0.92387953251f, S1=0.38268343236f, C2=0.70710678119f;
  h[5]  = twc<SGN>(h[5],  C1,-S1);
  h[6]  = twc<SGN>(h[6],  C2,-C2);
  h[7]  = twc<SGN>(h[7],  S1,-C1);
  h[9]  = twc<SGN>(h[9],  C2,-C2);
  h[10] = twc<SGN>(h[10], 0.f,-1.f);
  h[11] = twc<SGN>(h[11],-C2,-C2);
  h[13] = twc<SGN>(h[13], S1,-C1);
  h[14] = twc<SGN>(h[14],-C2,-C2);
  h[15] = twc<SGN>(h[15],-C1, S1);
#pragma unroll
  for (int q=0;q<4;q++){
    float2 a=h[q], b=h[4+q], c=h[8+q], d=h[12+q];
    fft4<SGN>(a,b,c,d);
    v[q]=a; v[q+4]=b; v[q+8]=c; v[q+12]=d;
  }
}

// ---------------- hoisted twiddles ----------------
// tw[q-1] = exp(-i*2pi*t*q/256) (forward/SGN=-1 set). Both fft256 calls in a
// pass reuse it: SGN<0 uses cmul, SGN>0 uses cmulc (conjugate). Computed ONCE
// per kernel (serial 15-cmul chain hides under the independent state loads).
__device__ __forceinline__ void make_tw(float2 tw[15], int t){
  float s0, c0;
  sincosf(0.0245436926f * (float)t, &s0, &c0);   // 2*pi/256 * t
  float2 w1 = make_float2(c0, -s0);
  tw[0] = w1;
#pragma unroll
  for (int q=1;q<15;q++) tw[q] = cmul(tw[q-1], w1);
}

// ---------------- fft256 via LDS transpose, fp32 buffers ----------------
// Round-6 lesson: fp32 LDS beats half2-packed (cvt tax on VALU-heavy kernel).
// Round-7 lesson: BARRIER=0 for wave-private groups is safe and free.
template<int SGN, int BARRIER>
__device__ __forceinline__ void fft256(float2 v[16], float* Tr, float* Ti, int g, int t,
                                       const float2 tw[15]){
  fft16<SGN>(v);
#pragma unroll
  for (int q=1;q<16;q++){
    v[q] = (SGN < 0) ? cmul(v[q], tw[q-1]) : cmulc(v[q], tw[q-1]);
  }
  int base = g*257;
  if (BARRIER) __syncthreads();
#pragma unroll
  for (int k1=0;k1<16;k1++){
    int o = base + t*16 + (k1^t);
    Tr[o] = v[k1].x; Ti[o] = v[k1].y;
  }
  if (BARRIER) __syncthreads();
#pragma unroll
  for (int n1=0;n1<16;n1++){
    int o = base + n1*16 + (t^n1);
    v[n1] = make_float2(Tr[o], Ti[o]);
  }
  fft16<SGN>(v);
  if (SGN > 0){
#pragma unroll
    for (int q=0;q<16;q++) v[q] = cscale(v[q], 1.f/256.f);
  }
}

__device__ __forceinline__ float ffreq(int i){ return (float)(i < 128 ? i : i - 256) * 0.0390625f; }

#define LDS_F 4112
#define KMAX  1.26903553299f   // 0.025/0.0197
#define PHCONST 0.123778191f   // pi*lambda*dz = pi*0.0197*2.0

// ================== main path ==================
// d_out scratch layout (overwritten by the final pass, which writes every byte):
//   probe  at d_out + 0        (512 KB, float2[256*256])
//   ptmp   at d_out + 512 KB   (512 KB)
// ws layout: state [B,256,256] half2 at 0; ttab (8x1024x1024 float2, 64 MB) after.
// H is SEPARABLE (exp(i*PH*(kx^2+ky^2)) = h1(kx)*h1(ky)): col kernels build a
// 256-entry h1 table in LDS (1 sincosf/thread) -- no 2D htab, no htab kernel,
// and the fused final pass has no scratch-read race.

// ---------------- probe rows (wave-private FFT groups: no barriers) ----------------
__global__ void __launch_bounds__(256) probe_rowsF(const void* defocus, const void* Cs,
                                                   const void* astig_mag, const void* astig_angle,
                                                   const void* ap_smooth, const void* ampflag,
                                                   float2* tmp){
  __shared__ float Tr[LDS_F], Ti[LDS_F];
  bool f64 = is_f64(ampflag);
  int tid = threadIdx.x, g = tid>>4, t = tid&15;
  int r = blockIdx.x*16 + g;
  double df = lds_scalar(defocus, f64), cs = lds_scalar(Cs, f64);
  double am = lds_scalar(astig_mag, f64), aa = lds_scalar(astig_angle, f64);
  float sm = fabsf((float)lds_scalar(ap_smooth, f64)) + 0.01f;
  const double LAMd = 0.0197;
  float kxv = ffreq(r);
  float2 v[16];
#pragma unroll
  for (int j=0;j<16;j++){
    int c = t + 16*j;
    float kyv = ffreq(c);
    double k2 = (double)kxv*kxv + (double)kyv*kyv;
    float k  = sqrtf((float)k2);
    double ang = atan2((double)kyv, (double)kxv);
    double chi = M_PI*LAMd*df*k2
               + 0.5*M_PI*LAMd*LAMd*LAMd*(cs*1e6)*k2*k2
               + M_PI*LAMd*am*k2*cos(2.0*(ang - aa));
    float ap = 1.f/(1.f + expf(-(KMAX - k)/(KMAX*sm)));
    double sc = sin(chi), cc = cos(chi);
    v[j] = make_float2(ap*(float)cc, ap*(float)sc);
  }
  float2 tw[15]; make_tw(tw, t);
  fft256<1,0>(v, Tr, Ti, g, t, tw);
#pragma unroll
  for (int j=0;j<16;j++) tmp[(r<<8) + t + 16*j] = v[j];
}

// ---------------- probe cols (groups span waves: barriers required) -------------
__global__ void __launch_bounds__(256) probe_colsF(const float2* tmp, float2* probe_out,
                                                   const void* ap_smooth, const void* ampflag){
  __shared__ float Tr[LDS_F], Ti[LDS_F];
  bool f64 = is_f64(ampflag);
  int tid = threadIdx.x, xl = tid&15, t = tid>>4;
  int cx = blockIdx.x*16 + xl;
  float sm = fabsf((float)lds_scalar(ap_smooth, f64)) + 0.01f;
  float S = 0.f;
  for (int i = tid; i < 65536; i += 256){
    float kx = ffreq(i>>8), ky = ffreq(i&255);
    float k = sqrtf(kx*kx + ky*ky);
    float ap = 1.f/(1.f + expf(-(KMAX - k)/(KMAX*sm)));
    S += ap*ap;
  }
#pragma unroll
  for (int off=32; off>0; off>>=1) S += __shfl_down(S, off);
  if ((tid&63)==0) Tr[tid>>6] = S;
  __syncthreads();
  float scale = 256.f * rsqrtf(Tr[0]+Tr[1]+Tr[2]+Tr[3]);
  float2 v[16];
#pragma unroll
  for (int j=0;j<16;j++) v[j] = tmp[((t+16*j)<<8) + cx];
  float2 tw[15]; make_tw(tw, t);
  fft256<1,1>(v, Tr, Ti, xl, t, tw);
  int csh = (cx + 128) & 255;
#pragma unroll
  for (int j=0;j<16;j++){
    int y = t + 16*j;
    probe_out[(((y+128)&255)<<8) + csh] = cscale(v[j], scale);
  }
}

// ---------------- transmission table (8x1024x1024 float2, computed once) --------
__global__ void __launch_bounds__(256) build_ttabF(const void* amp, const void* phase,
                                                   float2* ttab){
  bool f64 = is_f64(amp);
  int tid = threadIdx.x;
#pragma unroll
  for (int k=0;k<4;k++){
    size_t i = (size_t)blockIdx.x*1024 + tid + 256*k;
    float A = ldf(amp, i, f64);
    float P = ldf(phase, i, f64);
    float sp, cp; sincosf(P, &sp, &cp);
    ttab[i] = make_float2(A*cp, A*sp);
  }
}

// ---------------- row pass: transmission PREFETCHED before FFT#1; NO barriers ----
template<int H>
__global__ void __launch_bounds__(256) row_passT(const void* amp, const void* phase,
                                                 const void* spos, const void* sidx,
                                                 void* state, const float2* probe,
                                                 const float2* ttab, int s, int first,
                                                 int use_tt){
  __shared__ float Tr[LDS_F], Ti[LDS_F];
  bool f64 = is_f64(amp);
  bool i64 = is_i64(spos);
  int tid = threadIdx.x, g = tid>>4, t = tid&15;
  int b = blockIdx.y;
  int y = blockIdx.x*16 + g;
  int n = ldi(sidx, b, i64);
  int py = ldi(spos, 2*(size_t)n, i64), px = ldi(spos, 2*(size_t)n+1, i64);
  size_t rowbase = ((size_t)s<<20) + (size_t)(py+y)*1024 + px;
  float2 tv[16];
  if (use_tt){
#pragma unroll
    for (int j=0;j<16;j++) tv[j] = ttab[rowbase + t + 16*j];
  } else {
#pragma unroll
    for (int j=0;j<16;j++){
      int x = t + 16*j;
      float A = ldf(amp,   rowbase + x, f64);
      float P = ldf(phase, rowbase + x, f64);
      float sp, cp; sincosf(P, &sp, &cp);
      tv[j] = make_float2(A*cp, A*sp);
    }
  }
  size_t ib = (size_t)b << 16;
  float2 tw[15]; make_tw(tw, t);
  float2 v[16];
  if (first){
#pragma unroll
    for (int j=0;j<16;j++) v[j] = probe[(y<<8) + t + 16*j];
  } else {
#pragma unroll
    for (int j=0;j<16;j++) v[j] = ld_state<H>(state, ib + (y<<8) + t + 16*j);
    fft256<1,0>(v, Tr, Ti, g, t, tw);
  }
#pragma unroll
  for (int j=0;j<16;j++) v[j] = cmul(v[j], tv[j]);
  fft256<-1,0>(v, Tr, Ti, g, t, tw);
#pragma unroll
  for (int j=0;j<16;j++) st_state<H>(state, ib + (y<<8) + t + 16*j, v[j]);
}

// ---------------- middle col pass: FFTc, xH (separable LDS h1), iFFTc ----------
template<int H>
__global__ void __launch_bounds__(256) col_passT(void* state){
  __shared__ float Tr[LDS_F], Ti[LDS_F];
  __shared__ float2 h1[256];
  int tid = threadIdx.x, xl = tid&15, t = tid>>4;
  int b = blockIdx.y;
  int cx = blockIdx.x*16 + xl;
  size_t ib = (size_t)b << 16;
  // fill h1: exp(i*PH*k^2) per 1D frequency (barrier inside fft256 covers the fill)
  {
    float kk = ffreq(tid);
    float a = PHCONST * kk * kk;
    float sa, ca; sincosf(a, &sa, &ca);
    h1[tid] = make_float2(ca, sa);
  }
  float2 tw[15]; make_tw(tw, t);
  float2 v[16];
#pragma unroll
  for (int j=0;j<16;j++) v[j] = ld_state<H>(state, ib + ((t+16*j)<<8) + cx);
  fft256<-1,1>(v, Tr, Ti, xl, t, tw);
  float2 hx = h1[cx & 255];
#pragma unroll
  for (int j=0;j<16;j++) v[j] = cmul(v[j], cmul(h1[t + 16*j], hx));
  fft256<1,1>(v, Tr, Ti, xl, t, tw);
#pragma unroll
  for (int j=0;j<16;j++) st_state<H>(state, ib + ((t+16*j)<<8) + cx, v[j]);
}

// ---------------- FINAL col pass: psi = fft2(exit7) * H ------------------------
// Algebraic fusion: psi = fft2(ifft2(fft2(exit7)*H)) = fft2(exit7)*H -- the old
// col7 (FFTc xH iFFTc, store) + col8 (FFTc, stout) pair contained a cancelling
// iFFTc/FFTc: one whole 48us pass + 134MB traffic deleted.
template<int H>
__global__ void __launch_bounds__(256) col_finT(void* state, void* outp){
  __shared__ float Tr[LDS_F], Ti[LDS_F];
  __shared__ float2 h1[256];
  int tid = threadIdx.x, xl = tid&15, t = tid>>4;
  int b = blockIdx.y;
  int cx = blockIdx.x*16 + xl;
  size_t ib = (size_t)b << 16;
  {
    float kk = ffreq(tid);
    float a = PHCONST * kk * kk;
    float sa, ca; sincosf(a, &sa, &ca);
    h1[tid] = make_float2(ca, sa);
  }
  float2 tw[15]; make_tw(tw, t);
  float2 v[16];
#pragma unroll
  for (int j=0;j<16;j++) v[j] = ld_state<H>(state, ib + ((t+16*j)<<8) + cx);
  fft256<-1,1>(v, Tr, Ti, xl, t, tw);
  float2 hx = h1[cx & 255];
#pragma unroll
  for (int j=0;j<16;j++){
    float2 r = cmul(v[j], cmul(h1[t + 16*j], hx));
    stout(outp, ib + ((t+16*j)<<8) + cx, r);
  }
}

template<int H>
static void run_new(const void* amp, const void* phase,
                    const void* df, const void* cs, const void* am, const void* aa,
                    const void* sm, const void* spos, const void* sidx, int B,
                    void* state, float2* ttab, int use_tt,
                    void* dout, hipStream_t stream){
  char* dob = (char*)dout;
  float2* probe = (float2*)dob;
  float2* ptmp  = (float2*)(dob + 524288);
  probe_rowsF<<<16, 256, 0, stream>>>(df, cs, am, aa, sm, amp, ptmp);
  probe_colsF<<<16, 256, 0, stream>>>(ptmp, probe, sm, amp);
  if (use_tt) build_ttabF<<<8192, 256, 0, stream>>>(amp, phase, ttab);
  dim3 grid(16, B);
  row_passT<H><<<grid, 256, 0, stream>>>(amp, phase, spos, sidx, state, probe, ttab, 0, 1, use_tt);
  col_passT<H><<<grid, 256, 0, stream>>>(state);
  for (int s = 1; s < 7; s++){
    row_passT<H><<<grid, 256, 0, stream>>>(amp, phase, spos, sidx, state, probe, ttab, s, 0, use_tt);
    col_passT<H><<<grid, 256, 0, stream>>>(state);
  }
  row_passT<H><<<grid, 256, 0, stream>>>(amp, phase, spos, sidx, state, probe, ttab, 7, 0, use_tt);
  col_finT<H><<<grid, 256, 0, stream>>>(state, dout);
}

extern "C" void kernel_launch(void* const* d_in, const int* in_sizes, int n_in,
                              void* d_out, int out_size, void* d_ws, size_t ws_size,
                              hipStream_t stream) {
  const void* amp   = d_in[0];
  const void* phase = d_in[1];
  const void* df    = d_in[2];
  const void* cs    = d_in[3];
  const void* am    = d_in[4];
  const void* aa    = d_in[5];
  const void* sm    = d_in[6];
  const void* spos  = d_in[7];
  const void* sidx  = d_in[8];
  int B = in_sizes[8];
  (void)out_size; (void)n_in;

  size_t stateH = (size_t)B * 65536 * 4;            // fp16 state [B,256,256] c32 (half2)
  const size_t ttabB = (size_t)8 * 1024 * 1024 * 8; // 64 MB transmission table
  if (ws_size >= stateH + ttabB){
    void*   state = d_ws;
    float2* ttab  = (float2*)((char*)d_ws + stateH);
    run_new<1>(amp, phase, df, cs, am, aa, sm, spos, sidx, B,
               state, ttab, 1, d_out, stream);
  } else if (ws_size >= stateH){
    run_new<1>(amp, phase, df, cs, am, aa, sm, spos, sidx, B,
               d_ws, (float2*)d_ws, 0, d_out, stream);
  } else {
    // no workspace: fp16 state lives in d_out itself (256KB/slot), tables inline
    run_new<1>(amp, phase, df, cs, am, aa, sm, spos, sidx, B,
               d_out, (float2*)d_out, 0, d_out, stream);
  }
}